// Round 4
// baseline (393.854 us; speedup 1.0000x reference)
//
#include <hip/hip_runtime.h>

// out[b,k,l,f] = x[b, src(k,l), f], B=32, L=128, F=64, K=2L=256, fp32.
//   k <  L: src = (l - k) mod L   (cyclic)
//   k >= L: src = (k - l) mod L   (reflected)
//
// Round-6: CALIBRATION BUILD. Three radically different store strategies
// (scattered multicast, slice-linear cached, slice-linear nt) all measured
// ~90us of total-minus-fill, and the kernel's own dispatch has NEVER been
// visible in the rocprof top-5 (all slots taken by ~162-173us fillBuffer
// re-poisons). The ~90us residual = kernel + dozens of tiny restore
// dispatches (per rocprof.md, hidden by --top-k). Unknown: is the kernel
// ~45us (write roofline: 256 MiB @ 6.5 TB/s) with ~45us graph overhead,
// or ~90us with a real 2x inefficiency (e.g. read-for-ownership)?
//
// This build runs the store pass 5x (asm memory clobber between passes
// blocks DSE; every pass writes the same correct values, so correctness
// holds). Effects: (a) kernel time ~5x -> its row ENTERS the top-5 and we
// finally read its dur/FETCH_SIZE/WRITE_SIZE; (b) dur_us-baseline ~= 4x
// per-pass time.
//
// Pre-committed readout:
//   dur ~420-440, kernel row ~225us, WRITE~1.25GiB, FETCH small
//       -> pass-1 kernel already at roofline; declare ROOFLINE next round.
//   dur ~600-650, kernel row ~450us, FETCH ~ WRITE ~ 1.25GiB
//       -> RFO convicted; fix = buffer_store flag sweep.
//   dur ~300-350, WRITE << 1.25GiB -> L3 absorbs repeats; reason from
//       the kernel row directly.

typedef float f32x4 __attribute__((ext_vector_type(4)));

__global__ __launch_bounds__(256) void SymmetryExpansion_kernel(
    const f32x4* __restrict__ x, f32x4* __restrict__ out) {
    unsigned t  = threadIdx.x;
    unsigned f4 = t & 15u;        // float4 chunk within F=64
    unsigned w  = t >> 4;         // l-group / row-group within block, 0..15

    unsigned blk   = blockIdx.x;
    unsigned kbsel = blk & 31u;   // 0..15 cyclic, 16..31 reflected
    unsigned b     = blk >> 5;    // batch

    bool refl   = (kbsel >= 16u);
    unsigned kb = refl ? (kbsel + 112u) : kbsel;  // 128..143 | 0..15

    // Held source rows:
    //   cyclic   : row_j = (w - kb + 16*j) mod 128
    //   reflected: row_j = (kb - w + 16*j) mod 128
    unsigned rbase = refl ? (kb - w) : (w + 128u - kb);

    // x is (32,128,64) fp32 -> float4 index (b<<11)|(row<<4)|f4
    const f32x4* xb = x + (b << 11) + f4;
    f32x4 r[8];
#pragma unroll
    for (unsigned j = 0; j < 8u; ++j)
        r[j] = xb[((rbase + (j << 4)) & 127u) << 4];

    // out float4 index: (b<<19)|(k<<11)|(l<<4)|f4. Slice m is k = kb+16m
    // (stride 16 slices = 1<<15 float4). Thread t's store offsets within a
    // slice are t + 256*j2 -> the workgroup covers the 32 KiB slice linearly.
    f32x4* ob = out + (b << 19) + (kb << 11) + t;

#pragma unroll 1
    for (int pass = 0; pass < 5; ++pass) {
        if (!refl) {
            // value at l = w + 16*j2 is x[b,(l-k)&127] = r[(j2-m)&7]
#pragma unroll
            for (unsigned m = 0; m < 8u; ++m)
#pragma unroll
                for (unsigned j2 = 0; j2 < 8u; ++j2)
                    ob[(m << 15) + (j2 << 8)] = r[(j2 - m) & 7u];
        } else {
            // value at l = w + 16*j2 is x[b,(k-l)&127] = r[(m-j2)&7]
#pragma unroll
            for (unsigned m = 0; m < 8u; ++m)
#pragma unroll
                for (unsigned j2 = 0; j2 < 8u; ++j2)
                    ob[(m << 15) + (j2 << 8)] = r[(m - j2) & 7u];
        }
        asm volatile("" ::: "memory");  // block dead-store elimination
    }
}

extern "C" void kernel_launch(void* const* d_in, const int* in_sizes, int n_in,
                              void* d_out, int out_size, void* d_ws, size_t ws_size,
                              hipStream_t stream) {
    const f32x4* x = (const f32x4*)d_in[0];
    f32x4* out = (f32x4*)d_out;
    dim3 grid(1024), block(256);
    hipLaunchKernelGGL(SymmetryExpansion_kernel, grid, block, 0, stream, x, out);
}

// Round 5
// 253.852 us; speedup vs baseline: 1.5515x; 1.5515x over previous
//
#include <hip/hip_runtime.h>

// out[b,k,l,f] = x[b, src(k,l), f], B=32, L=128, F=64, K=2L=256, fp32.
//   k <  L: src = (l - k) mod L   (cyclic)
//   k >= L: src = (k - l) mod L   (reflected)
//
// FINAL (round-7): single-pass slice-linear multicast — calibration-proven
// at the write roofline.
//
// Evidence ledger:
//  - dur_us decomposes as ~165us re-poison fillBuffer + ~50us tiny restore
//    dispatches + KERNEL. Rounds 2-5: three radically different store
//    strategies (scattered multicast / slice-linear cached / slice-linear
//    nt) all landed within fill jitter -> kernel was never the variable.
//  - Round-6 calibration (5x store pass, memory clobber between passes):
//    kernel row visible at 196-198us, WRITE_SIZE = 1.25 GiB (5 x 256 MiB,
//    L3 did not absorb), FETCH_SIZE ~ 4.8 MB (NO read-for-ownership),
//    6.86 TB/s = 85.8% of HBM peak — ABOVE fillBuffer's 6.6 TB/s.
//    Marginal per-pass = (393.9-255.7)/4 = 34.5us vs the 256 MiB /
//    6.6-6.9 TB/s arithmetic floor of 37-39us.
//  => The store pass IS the roofline. Remaining dur_us is harness cost.
//
// Structure: block (b,kbsel) holds 8 source rows in registers; writes 8
// whole 32 KiB (b,k) slices end-to-end linearly (thread t -> slice_base +
// t + 256*j2). Register index (+/-(j2-m))&7 is compile-time after full
// unroll — no LDS, no per-store modulo, no runtime-indexed register array.
//
// Grid: 32 b x 32 kbsel = 1024 blocks x 256 thr. Per thread: 8 cached
// loads (L2-hit), 64 independent stores.

typedef float f32x4 __attribute__((ext_vector_type(4)));

__global__ __launch_bounds__(256) void SymmetryExpansion_kernel(
    const f32x4* __restrict__ x, f32x4* __restrict__ out) {
    unsigned t  = threadIdx.x;
    unsigned f4 = t & 15u;        // float4 chunk within F=64
    unsigned w  = t >> 4;         // l-group / row-group within block, 0..15

    unsigned blk   = blockIdx.x;
    unsigned kbsel = blk & 31u;   // 0..15 cyclic, 16..31 reflected
    unsigned b     = blk >> 5;    // batch

    bool refl   = (kbsel >= 16u);
    unsigned kb = refl ? (kbsel + 112u) : kbsel;  // 128..143 | 0..15

    // Held source rows:
    //   cyclic   : row_j = (w - kb + 16*j) mod 128
    //   reflected: row_j = (kb - w + 16*j) mod 128
    unsigned rbase = refl ? (kb - w) : (w + 128u - kb);

    // x is (32,128,64) fp32 -> float4 index (b<<11)|(row<<4)|f4
    const f32x4* xb = x + (b << 11) + f4;
    f32x4 r[8];
#pragma unroll
    for (unsigned j = 0; j < 8u; ++j)
        r[j] = xb[((rbase + (j << 4)) & 127u) << 4];

    // out float4 index: (b<<19)|(k<<11)|(l<<4)|f4. Slice m is k = kb+16m
    // (stride 16 slices = 1<<15 float4). Thread t's store offsets within a
    // slice are t + 256*j2 -> the workgroup covers the 32 KiB slice linearly.
    f32x4* ob = out + (b << 19) + (kb << 11) + t;
    if (!refl) {
        // value at l = w + 16*j2 is x[b,(l-k)&127] = r[(j2-m)&7]
#pragma unroll
        for (unsigned m = 0; m < 8u; ++m)
#pragma unroll
            for (unsigned j2 = 0; j2 < 8u; ++j2)
                ob[(m << 15) + (j2 << 8)] = r[(j2 - m) & 7u];
    } else {
        // value at l = w + 16*j2 is x[b,(k-l)&127] = r[(m-j2)&7]
#pragma unroll
        for (unsigned m = 0; m < 8u; ++m)
#pragma unroll
            for (unsigned j2 = 0; j2 < 8u; ++j2)
                ob[(m << 15) + (j2 << 8)] = r[(m - j2) & 7u];
    }
}

extern "C" void kernel_launch(void* const* d_in, const int* in_sizes, int n_in,
                              void* d_out, int out_size, void* d_ws, size_t ws_size,
                              hipStream_t stream) {
    const f32x4* x = (const f32x4*)d_in[0];
    f32x4* out = (f32x4*)d_out;
    dim3 grid(1024), block(256);
    hipLaunchKernelGGL(SymmetryExpansion_kernel, grid, block, 0, stream, x, out);
}